// Round 1
// baseline (17016.733 us; speedup 1.0000x reference)
//
#include <hip/hip_runtime.h>
#include <cstddef>
#include <cstdint>

#define NB 64
#define NS 512
#define NE 256
#define NH 1024
#define NH3 3072
#define NV 32000

// ---------------- tiled transpose: dst[C][R] = src[R][C] ----------------
__global__ __launch_bounds__(256) void transpose_k(const float* __restrict__ src,
                                                   float* __restrict__ dst,
                                                   int R, int C) {
    __shared__ float tile[32][33];
    const int tx = threadIdx.x & 31;
    const int ty = threadIdx.x >> 5;        // 0..7
    const int c0 = blockIdx.x * 32;
    const int r0 = blockIdx.y * 32;
#pragma unroll
    for (int i = 0; i < 32; i += 8) {
        int r = r0 + ty + i, c = c0 + tx;
        if (r < R && c < C) tile[ty + i][tx] = src[(size_t)r * C + c];
    }
    __syncthreads();
#pragma unroll
    for (int i = 0; i < 32; i += 8) {
        int c = c0 + ty + i, r = r0 + tx;
        if (c < C && r < R) dst[(size_t)c * R + r] = tile[tx][ty + i];
    }
}

// ---------------- one GRU timestep (fused gather + xproj + rec + gates) ----
// grid: 256 blocks = 32 unit-groups (fast axis, for XCD-L2 locality) x 8 batch-groups
// block: 256 threads; thread = (b_local = tid&7, j_local = tid>>3)
template <bool TR>
__global__ __launch_bounds__(256) void gru_step(
    const int* __restrict__ tokens, const float* __restrict__ emb,
    const float* __restrict__ Wk,   // TR: WkT[3072][256]  else Wk[256][3072]
    const float* __restrict__ Uk,   // TR: UkT[3072][1024] else Uk[1024][3072]
    const float* __restrict__ bias, // [2][3072]
    const float* __restrict__ h_in, // [64][1024]
    float* __restrict__ h_out,      // [64][1024]
    int s) {
    __shared__ float xs[8][NE + 4];
    __shared__ float hs[8][NH + 4];

    const int ug = blockIdx.x & 31;  // unit group: fast axis -> XCD = ug%8
    const int bg = blockIdx.x >> 5;  // batch group 0..7
    const int tid = threadIdx.x;

    // cooperative load: x rows (embedding gather) for 8 batches
    for (int i = tid; i < 8 * (NE / 4); i += 256) {
        const int bl = i / (NE / 4);
        const int e4 = i % (NE / 4);
        const int b = bg * 8 + bl;
        const int tok = tokens[b * NS + s];
        const float4 v = ((const float4*)(emb + (size_t)tok * NE))[e4];
        ((float4*)(xs[bl]))[e4] = v;
    }
    // cooperative load: h rows for 8 batches
    for (int i = tid; i < 8 * (NH / 4); i += 256) {
        const int bl = i / (NH / 4);
        const int k4 = i % (NH / 4);
        const int b = bg * 8 + bl;
        ((float4*)(hs[bl]))[k4] = ((const float4*)(h_in + (size_t)b * NH))[k4];
    }
    __syncthreads();

    const int bl = tid & 7;
    const int jl = tid >> 3;  // 0..31
    const int j = ug * 32 + jl;
    const int b = bg * 8 + bl;

    float az = bias[j] + bias[NH3 + j];
    float ar = bias[NH + j] + bias[NH3 + NH + j];
    float axh = bias[2 * NH + j];
    float arh = bias[NH3 + 2 * NH + j];

    if constexpr (TR) {
        const float4* xr4 = (const float4*)(xs[bl]);
        const float4* wz = (const float4*)(Wk + (size_t)j * NE);
        const float4* wr = (const float4*)(Wk + (size_t)(NH + j) * NE);
        const float4* wh = (const float4*)(Wk + (size_t)(2 * NH + j) * NE);
#pragma unroll 4
        for (int e = 0; e < NE / 4; ++e) {
            const float4 x4 = xr4[e];
            const float4 a = wz[e];
            const float4 c = wr[e];
            const float4 d = wh[e];
            az = fmaf(x4.x, a.x, az); az = fmaf(x4.y, a.y, az);
            az = fmaf(x4.z, a.z, az); az = fmaf(x4.w, a.w, az);
            ar = fmaf(x4.x, c.x, ar); ar = fmaf(x4.y, c.y, ar);
            ar = fmaf(x4.z, c.z, ar); ar = fmaf(x4.w, c.w, ar);
            axh = fmaf(x4.x, d.x, axh); axh = fmaf(x4.y, d.y, axh);
            axh = fmaf(x4.z, d.z, axh); axh = fmaf(x4.w, d.w, axh);
        }
        const float4* h4p = (const float4*)(hs[bl]);
        const float4* uz = (const float4*)(Uk + (size_t)j * NH);
        const float4* ur = (const float4*)(Uk + (size_t)(NH + j) * NH);
        const float4* uh = (const float4*)(Uk + (size_t)(2 * NH + j) * NH);
#pragma unroll 4
        for (int k = 0; k < NH / 4; ++k) {
            const float4 h4 = h4p[k];
            const float4 a = uz[k];
            const float4 c = ur[k];
            const float4 d = uh[k];
            az = fmaf(h4.x, a.x, az); az = fmaf(h4.y, a.y, az);
            az = fmaf(h4.z, a.z, az); az = fmaf(h4.w, a.w, az);
            ar = fmaf(h4.x, c.x, ar); ar = fmaf(h4.y, c.y, ar);
            ar = fmaf(h4.z, c.z, ar); ar = fmaf(h4.w, c.w, ar);
            arh = fmaf(h4.x, d.x, arh); arh = fmaf(h4.y, d.y, arh);
            arh = fmaf(h4.z, d.z, arh); arh = fmaf(h4.w, d.w, arh);
        }
    } else {
        for (int e = 0; e < NE; ++e) {
            const float xv = xs[bl][e];
            az = fmaf(xv, Wk[(size_t)e * NH3 + j], az);
            ar = fmaf(xv, Wk[(size_t)e * NH3 + NH + j], ar);
            axh = fmaf(xv, Wk[(size_t)e * NH3 + 2 * NH + j], axh);
        }
        for (int k = 0; k < NH; ++k) {
            const float hv = hs[bl][k];
            az = fmaf(hv, Uk[(size_t)k * NH3 + j], az);
            ar = fmaf(hv, Uk[(size_t)k * NH3 + NH + j], ar);
            arh = fmaf(hv, Uk[(size_t)k * NH3 + 2 * NH + j], arh);
        }
    }

    const float z = 1.0f / (1.0f + expf(-az));
    const float r = 1.0f / (1.0f + expf(-ar));
    const float hh = tanhf(axh + r * arh);
    const float hp = hs[bl][j];
    const bool m = tokens[b * NS + s] != 0;
    const float hn = m ? (z * hp + (1.0f - z) * hh) : hp;
    h_out[(size_t)b * NH + j] = hn;
}

// ---------------- out = h[64,1024] @ Wout[1024,32000] ----------------
__global__ __launch_bounds__(256) void out_mm(const float* __restrict__ h,
                                              const float* __restrict__ Wout,
                                              float* __restrict__ out) {
    const int col = blockIdx.x * 256 + threadIdx.x;  // 32000 = 125*256
    float acc[NB];
#pragma unroll
    for (int b = 0; b < NB; ++b) acc[b] = 0.0f;
    for (int k = 0; k < NH; ++k) {
        const float w = Wout[(size_t)k * NV + col];
#pragma unroll
        for (int b = 0; b < NB; ++b) acc[b] = fmaf(h[b * NH + k], w, acc[b]);
    }
#pragma unroll
    for (int b = 0; b < NB; ++b) out[(size_t)b * NV + col] = acc[b];
}

extern "C" void kernel_launch(void* const* d_in, const int* in_sizes, int n_in,
                              void* d_out, int out_size, void* d_ws, size_t ws_size,
                              hipStream_t stream) {
    const int* tokens = (const int*)d_in[0];
    const float* emb = (const float*)d_in[1];
    const float* Wk = (const float*)d_in[2];
    const float* Uk = (const float*)d_in[3];
    const float* bias = (const float*)d_in[4];
    const float* Wout = (const float*)d_in[5];
    float* out = (float*)d_out;

    const size_t ukt_sz = (size_t)NH3 * NH;  // floats
    const size_t wkt_sz = (size_t)NH3 * NE;
    const size_t h_sz = (size_t)NB * NH;
    const size_t need_bytes = (ukt_sz + wkt_sz + 2 * h_sz) * sizeof(float);

    float* ws = (float*)d_ws;
    const bool tr = (ws_size >= need_bytes);

    float* UkT = nullptr;
    float* WkT = nullptr;
    float* h0;
    if (tr) {
        UkT = ws;
        WkT = ws + ukt_sz;
        h0 = WkT + wkt_sz;
    } else {
        h0 = ws;  // requires >= 512 KiB workspace
    }
    float* h1 = h0 + h_sz;

    hipMemsetAsync(h0, 0, h_sz * sizeof(float), stream);

    if (tr) {
        transpose_k<<<dim3(NH3 / 32, NH / 32), 256, 0, stream>>>(Uk, UkT, NH, NH3);
        transpose_k<<<dim3(NH3 / 32, NE / 32), 256, 0, stream>>>(Wk, WkT, NE, NH3);
        for (int s = 0; s < NS; ++s) {
            const float* hin = (s & 1) ? h1 : h0;
            float* hout = (s & 1) ? h0 : h1;
            gru_step<true><<<256, 256, 0, stream>>>(tokens, emb, WkT, UkT, bias, hin, hout, s);
        }
    } else {
        for (int s = 0; s < NS; ++s) {
            const float* hin = (s & 1) ? h1 : h0;
            float* hout = (s & 1) ? h0 : h1;
            gru_step<false><<<256, 256, 0, stream>>>(tokens, emb, Wk, Uk, bias, hin, hout, s);
        }
    }
    out_mm<<<125, 256, 0, stream>>>(h0, Wout, out);
}

// Round 2
// 9299.141 us; speedup vs baseline: 1.8299x; 1.8299x over previous
//
#include <hip/hip_runtime.h>
#include <cstddef>
#include <cstdint>

#define NB 64
#define NS 512
#define NE 256
#define NH 1024
#define NH3 3072
#define NV 32000

#define NBT 8              // batches per block (register-blocked)
#define UT 16              // units per block
#define KS 16              // k-slices per block
#define KH (NH / KS)       // 64 h-elements per slice
#define KX (NE / KS)       // 16 x-elements per slice

// padded-row maps: insert 1 pad row per 64 (h) / per 16 (x) rows so the 4
// distinct k-slices within a wave land in distinct LDS bank groups.
__device__ __forceinline__ int hrow(int k) { return k + (k >> 6); }
__device__ __forceinline__ int xrow(int k) { return k + (k >> 4); }

// ---------------- one GRU timestep ----------------
// grid: 512 blocks = bg(8 batch-groups) * ug(64 unit-groups); blockIdx = bg*64+ug
// -> XCD = ug % 8 (stable L2 residency of each XCD's Uk slice across steps)
// block: 256 threads = ks(16 k-slices) * ul(16 units); 8 batches in registers.
__global__ __launch_bounds__(256) void gru_step2(
    const int* __restrict__ tokens, const float* __restrict__ emb,
    const float* __restrict__ Wk,   // [256][3072] row-major (original)
    const float* __restrict__ Uk,   // [1024][3072] row-major (original)
    const float* __restrict__ bias, // [2][3072]
    const float* __restrict__ h_in, // [64][1024]
    float* __restrict__ h_out,      // [64][1024]
    int s)
{
    __shared__ float hs[NH + NH / 64][NBT];   // [hrow(k)][b]  1040*8*4 = 33.3 KB
    __shared__ float xs[NE + NE / 16][NBT];   // [xrow(k)][b]   272*8*4 =  8.7 KB
    __shared__ float red[4][NBT][256];        // [gate][b][thread]      = 32.0 KB

    const int tid = threadIdx.x;
    const int ug = blockIdx.x & 63;
    const int bg = blockIdx.x >> 6;

    // ---- stage x rows (embedding gather), transposed+padded ----
    for (int i = tid; i < NBT * (NE / 4); i += 256) {
        const int bl = i >> 6;          // / (NE/4)
        const int e4 = i & 63;
        const int b = bg * NBT + bl;
        const int tok = tokens[b * NS + s];
        const float4 v = ((const float4*)(emb + (size_t)tok * NE))[e4];
        const int k0 = e4 * 4;          // all 4 in same 16-group? k0%16 in {0,4,8,12} -> yes
        xs[xrow(k0 + 0)][bl] = v.x;
        xs[xrow(k0 + 1)][bl] = v.y;
        xs[xrow(k0 + 2)][bl] = v.z;
        xs[xrow(k0 + 3)][bl] = v.w;
    }
    // ---- stage h rows, transposed+padded ----
    for (int i = tid; i < NBT * (NH / 4); i += 256) {
        const int bl = i >> 8;          // / (NH/4)
        const int k4 = i & 255;
        const int b = bg * NBT + bl;
        const float4 v = ((const float4*)(h_in + (size_t)b * NH))[k4];
        const int k0 = k4 * 4;          // 4 consecutive within one 64-group
        const int r = hrow(k0);
        hs[r + 0][bl] = v.x;
        hs[r + 1][bl] = v.y;
        hs[r + 2][bl] = v.z;
        hs[r + 3][bl] = v.w;
    }
    __syncthreads();

    const int ul = tid & 15;
    const int ks = tid >> 4;
    const int u = ug * UT + ul;

    float az[NBT], ar[NBT], axh[NBT], arh[NBT];
#pragma unroll
    for (int b = 0; b < NBT; ++b) { az[b] = 0.f; ar[b] = 0.f; axh[b] = 0.f; arh[b] = 0.f; }

    // ---- h part: k in [ks*64, ks*64+64), 3 gate columns, 8 batches ----
    {
        size_t off = (size_t)(ks * KH) * NH3 + u;
        const int r0 = ks * (KH + 1);   // hrow(ks*64) = ks*64 + ks
#pragma unroll 4
        for (int kk = 0; kk < KH; ++kk) {
            const float uz = Uk[off];
            const float ur = Uk[off + NH];
            const float uh = Uk[off + 2 * NH];
            float hv[8];
            *(float4*)&hv[0] = *(const float4*)&hs[r0 + kk][0];
            *(float4*)&hv[4] = *(const float4*)&hs[r0 + kk][4];
#pragma unroll
            for (int b = 0; b < NBT; ++b) {
                az[b] = fmaf(hv[b], uz, az[b]);
                ar[b] = fmaf(hv[b], ur, ar[b]);
                arh[b] = fmaf(hv[b], uh, arh[b]);
            }
            off += NH3;
        }
    }
    // ---- x part: k in [ks*16, ks*16+16) ----
    {
        size_t off = (size_t)(ks * KX) * NH3 + u;
        const int r0 = ks * (KX + 1);   // xrow(ks*16) = ks*16 + ks
#pragma unroll 4
        for (int kk = 0; kk < KX; ++kk) {
            const float wz = Wk[off];
            const float wr = Wk[off + NH];
            const float wh = Wk[off + 2 * NH];
            float xv[8];
            *(float4*)&xv[0] = *(const float4*)&xs[r0 + kk][0];
            *(float4*)&xv[4] = *(const float4*)&xs[r0 + kk][4];
#pragma unroll
            for (int b = 0; b < NBT; ++b) {
                az[b] = fmaf(xv[b], wz, az[b]);
                ar[b] = fmaf(xv[b], wr, ar[b]);
                axh[b] = fmaf(xv[b], wh, axh[b]);
            }
            off += NH3;
        }
    }

    // ---- deposit partials ----
#pragma unroll
    for (int b = 0; b < NBT; ++b) {
        red[0][b][tid] = az[b];
        red[1][b][tid] = ar[b];
        red[2][b][tid] = axh[b];
        red[3][b][tid] = arh[b];
    }
    __syncthreads();

    // ---- reduce + gates: 128 threads = 16 units x 8 batches ----
    if (tid < 128) {
        const int ul2 = tid & 15;
        const int bl = tid >> 4;
        const int u2 = ug * UT + ul2;
        const int b = bg * NBT + bl;
        float sz = 0.f, sr = 0.f, sxh = 0.f, srh = 0.f;
#pragma unroll
        for (int k2 = 0; k2 < KS; ++k2) {
            const int t2 = k2 * 16 + ul2;
            sz += red[0][bl][t2];
            sr += red[1][bl][t2];
            sxh += red[2][bl][t2];
            srh += red[3][bl][t2];
        }
        sz += bias[u2] + bias[NH3 + u2];
        sr += bias[NH + u2] + bias[NH3 + NH + u2];
        sxh += bias[2 * NH + u2];
        srh += bias[NH3 + 2 * NH + u2];

        const float z = 1.0f / (1.0f + expf(-sz));
        const float r = 1.0f / (1.0f + expf(-sr));
        const float hh = tanhf(sxh + r * srh);
        const float hp = hs[hrow(u2)][bl];
        const bool m = tokens[b * NS + s] != 0;
        const float hn = m ? (z * hp + (1.0f - z) * hh) : hp;
        h_out[(size_t)b * NH + u2] = hn;
    }
}

// ---------------- out = h[64,1024] @ Wout[1024,32000] ----------------
__global__ __launch_bounds__(256) void out_mm(const float* __restrict__ h,
                                              const float* __restrict__ Wout,
                                              float* __restrict__ out) {
    const int col = blockIdx.x * 256 + threadIdx.x;  // 32000 = 125*256
    float acc[NB];
#pragma unroll
    for (int b = 0; b < NB; ++b) acc[b] = 0.0f;
    for (int k = 0; k < NH; ++k) {
        const float w = Wout[(size_t)k * NV + col];
#pragma unroll
        for (int b = 0; b < NB; ++b) acc[b] = fmaf(h[b * NH + k], w, acc[b]);
    }
#pragma unroll
    for (int b = 0; b < NB; ++b) out[(size_t)b * NV + col] = acc[b];
}

extern "C" void kernel_launch(void* const* d_in, const int* in_sizes, int n_in,
                              void* d_out, int out_size, void* d_ws, size_t ws_size,
                              hipStream_t stream) {
    const int* tokens = (const int*)d_in[0];
    const float* emb = (const float*)d_in[1];
    const float* Wk = (const float*)d_in[2];
    const float* Uk = (const float*)d_in[3];
    const float* bias = (const float*)d_in[4];
    const float* Wout = (const float*)d_in[5];
    float* out = (float*)d_out;

    const size_t h_sz = (size_t)NB * NH;
    float* h0 = (float*)d_ws;
    float* h1 = h0 + h_sz;

    hipMemsetAsync(h0, 0, h_sz * sizeof(float), stream);

    for (int s = 0; s < NS; ++s) {
        const float* hin = (s & 1) ? h1 : h0;
        float* hout = (s & 1) ? h0 : h1;
        gru_step2<<<512, 256, 0, stream>>>(tokens, emb, Wk, Uk, bias, hin, hout, s);
    }
    out_mm<<<125, 256, 0, stream>>>(h0, Wout, out);
}

// Round 3
// 4302.043 us; speedup vs baseline: 3.9555x; 2.1616x over previous
//
#include <hip/hip_runtime.h>
#include <cstddef>
#include <cstdint>

#define NB 64
#define NS 512
#define NE 256
#define NH 1024
#define NH3 3072
#define NV 32000

typedef unsigned short u16;
typedef unsigned int u32;
typedef __attribute__((ext_vector_type(8))) short short8v;
typedef __attribute__((ext_vector_type(4))) float f32x4;

__device__ __forceinline__ u16 f2bf(float x) {
    u32 u = __float_as_uint(x);
    u32 r = (u + 0x7FFFu + ((u >> 16) & 1u)) >> 16;   // RNE
    return (u16)r;
}
__device__ __forceinline__ float bf2f(u16 h) { return __uint_as_float(((u32)h) << 16); }

// ============================================================================
// MFMA path. K-concat: k in [0,1024) = h (recurrent), [1024,1280) = x.
// Per 16-unit group g: 4 output tiles {z(K=1280), r(K=1280), xh(K=256), rh(K=1024)}.
// Packed B layout: [g:64][slot:120][lane:64][j:8] bf16 (hi and lo arrays).
//   slots 0..39: z kc=slot | 40..79: r kc=slot-40 | 80..87: xh kc=slot-48 | 88..119: rh kc=slot-88
// Fragment mapping (16x16x32): lane l -> row/col = l&15, k = (l>>4)*8 + j.
// ============================================================================

__global__ __launch_bounds__(256) void pack_uk(const float* __restrict__ Wk,
                                               const float* __restrict__ Uk,
                                               u16* __restrict__ Bh, u16* __restrict__ Bl) {
    const int idx = blockIdx.x * 256 + threadIdx.x;   // 64*120*512 total
    const int j = idx & 7;
    const int lane = (idx >> 3) & 63;
    const int slot = (idx >> 9) % 120;
    const int g = idx / (120 * 512);
    int tile, kc;
    if (slot < 40) { tile = 0; kc = slot; }
    else if (slot < 80) { tile = 1; kc = slot - 40; }
    else if (slot < 88) { tile = 2; kc = slot - 48; }   // xh: kc = 32 + (slot-80)
    else { tile = 3; kc = slot - 88; }                   // rh
    const int k = kc * 32 + ((lane >> 4) << 3) + j;
    const int uu = g * 16 + (lane & 15);
    const int col = (tile == 0) ? uu : (tile == 1) ? (NH + uu) : (2 * NH + uu);
    const float v = (k < NH) ? Uk[(size_t)k * NH3 + col]
                             : Wk[(size_t)(k - NH) * NH3 + col];
    const u16 hi = f2bf(v);
    Bh[idx] = hi;
    Bl[idx] = f2bf(v - bf2f(hi));
}

// X fragments for all steps: [s:512][mg:4][kcx:8][lane:64][j:8] bf16 hi/lo
__global__ __launch_bounds__(256) void pack_x(const int* __restrict__ tokens,
                                              const float* __restrict__ emb,
                                              u16* __restrict__ Xh, u16* __restrict__ Xl) {
    const int idx = blockIdx.x * 256 + threadIdx.x;   // 512*4*8*512 total
    const int j = idx & 7;
    const int lane = (idx >> 3) & 63;
    const int kcx = (idx >> 9) & 7;
    const int mg = (idx >> 12) & 3;
    const int s = idx >> 14;
    const int b = mg * 16 + (lane & 15);
    const int e = kcx * 32 + ((lane >> 4) << 3) + j;
    const int tok = tokens[b * NS + s];
    const float v = emb[(size_t)tok * NE + e];
    const u16 hi = f2bf(v);
    Xh[idx] = hi;
    Xl[idx] = f2bf(v - bf2f(hi));
}

// one GRU step. grid 256 = mg(4) * g(64), blockIdx = mg*64+g -> XCD = g%8.
// 512 threads = 8 waves; wave w handles kc = w + 8t, t=0..4 (t<4: h-part, t==4: x-part).
__global__ __launch_bounds__(512) void gru_step3(
    const int* __restrict__ tokens,
    const u16* __restrict__ Bh, const u16* __restrict__ Bl,
    const u16* __restrict__ Xh, const u16* __restrict__ Xl,
    const float* __restrict__ bias,
    const float* __restrict__ hcur,                   // [64][1024] fp32
    const u16* __restrict__ hsh, const u16* __restrict__ hsl,  // [mg:4][kc:32][lane:64][j:8]
    float* __restrict__ hnext,
    u16* __restrict__ hnh, u16* __restrict__ hnl,
    int s)
{
    __shared__ f32x4 red[8][4][64];   // 32 KB
    __shared__ f32x4 preS[4][64];     // 4 KB

    const int g = blockIdx.x & 63;
    const int mg = blockIdx.x >> 6;
    const int tid = threadIdx.x;
    const int w = tid >> 6;
    const int lane = tid & 63;

    f32x4 accz = {0.f, 0.f, 0.f, 0.f};
    f32x4 accr = accz, accxh = accz, accrh = accz;

    const size_t bbase = (size_t)g * 120 * 512;
    const size_t laneo = (size_t)lane * 8;

#pragma unroll
    for (int t = 0; t < 5; ++t) {
        const int kc = w + 8 * t;
        // ---- A fragment (hi, lo) ----
        size_t aoff;
        const u16 *pah, *pal;
        if (t < 4) {
            aoff = ((size_t)(mg * 32 + kc) * 64) * 8 + laneo;
            pah = hsh + aoff; pal = hsl + aoff;
        } else {
            aoff = ((((size_t)s * 4 + mg) * 8 + (kc - 32)) * 64) * 8 + laneo;
            pah = Xh + aoff; pal = Xl + aoff;
        }
        const short8v Ah = *(const short8v*)pah;
        const short8v Al = *(const short8v*)pal;
        // ---- B fragments: z, r, and (rh | xh) ----
        const size_t oz = bbase + (size_t)kc * 512 + laneo;
        const size_t orr = bbase + (size_t)(40 + kc) * 512 + laneo;
        const size_t o3 = bbase + (size_t)((t < 4) ? (88 + kc) : (48 + kc)) * 512 + laneo;
        const short8v Bzh = *(const short8v*)(Bh + oz);
        const short8v Bzl = *(const short8v*)(Bl + oz);
        const short8v Brh_ = *(const short8v*)(Bh + orr);
        const short8v Brl_ = *(const short8v*)(Bl + orr);
        const short8v B3h = *(const short8v*)(Bh + o3);
        const short8v B3l = *(const short8v*)(Bl + o3);

        accz = __builtin_amdgcn_mfma_f32_16x16x32_bf16(Ah, Bzh, accz, 0, 0, 0);
        accr = __builtin_amdgcn_mfma_f32_16x16x32_bf16(Ah, Brh_, accr, 0, 0, 0);
        if (t < 4) {
            accrh = __builtin_amdgcn_mfma_f32_16x16x32_bf16(Ah, B3h, accrh, 0, 0, 0);
            accrh = __builtin_amdgcn_mfma_f32_16x16x32_bf16(Al, B3h, accrh, 0, 0, 0);
            accrh = __builtin_amdgcn_mfma_f32_16x16x32_bf16(Ah, B3l, accrh, 0, 0, 0);
        } else {
            accxh = __builtin_amdgcn_mfma_f32_16x16x32_bf16(Ah, B3h, accxh, 0, 0, 0);
            accxh = __builtin_amdgcn_mfma_f32_16x16x32_bf16(Al, B3h, accxh, 0, 0, 0);
            accxh = __builtin_amdgcn_mfma_f32_16x16x32_bf16(Ah, B3l, accxh, 0, 0, 0);
        }
        accz = __builtin_amdgcn_mfma_f32_16x16x32_bf16(Al, Bzh, accz, 0, 0, 0);
        accz = __builtin_amdgcn_mfma_f32_16x16x32_bf16(Ah, Bzl, accz, 0, 0, 0);
        accr = __builtin_amdgcn_mfma_f32_16x16x32_bf16(Al, Brh_, accr, 0, 0, 0);
        accr = __builtin_amdgcn_mfma_f32_16x16x32_bf16(Ah, Brl_, accr, 0, 0, 0);
    }

    red[w][0][lane] = accz;
    red[w][1][lane] = accr;
    red[w][2][lane] = accxh;
    red[w][3][lane] = accrh;
    __syncthreads();

    if (tid < 256) {
        const int tt = tid >> 6;
        const int ll = tid & 63;
        f32x4 sum = red[0][tt][ll];
#pragma unroll
        for (int w2 = 1; w2 < 8; ++w2) {
            const f32x4 v = red[w2][tt][ll];
            sum.x += v.x; sum.y += v.y; sum.z += v.z; sum.w += v.w;
        }
        preS[tt][ll] = sum;
    }
    __syncthreads();

    if (tid < 64) {
        const int ll = tid;
        const int u = g * 16 + (ll & 15);
        const f32x4 pz = preS[0][ll];
        const f32x4 pr = preS[1][ll];
        const f32x4 pxh = preS[2][ll];
        const f32x4 prh = preS[3][ll];
        const float bz = bias[u] + bias[NH3 + u];
        const float br = bias[NH + u] + bias[NH3 + NH + u];
        const float bxh = bias[2 * NH + u];
        const float brh = bias[NH3 + 2 * NH + u];
        const int kcu = u >> 5;
        const int lhi = ((u & 31) >> 3) << 4;
        const int j2 = u & 7;
#pragma unroll
        for (int j = 0; j < 4; ++j) {
            const int brow = ((ll >> 4) << 2) + j;    // 0..15 within mg
            const int b = mg * 16 + brow;
            const float pzv = (j == 0) ? pz.x : (j == 1) ? pz.y : (j == 2) ? pz.z : pz.w;
            const float prv = (j == 0) ? pr.x : (j == 1) ? pr.y : (j == 2) ? pr.z : pr.w;
            const float pxv = (j == 0) ? pxh.x : (j == 1) ? pxh.y : (j == 2) ? pxh.z : pxh.w;
            const float phv = (j == 0) ? prh.x : (j == 1) ? prh.y : (j == 2) ? prh.z : prh.w;
            const float z = 1.0f / (1.0f + expf(-(pzv + bz)));
            const float r = 1.0f / (1.0f + expf(-(prv + br)));
            const float hh = tanhf(pxv + bxh + r * (phv + brh));
            const float hp = hcur[(size_t)b * NH + u];
            const bool m = tokens[b * NS + s] != 0;
            const float hn = m ? (z * hp + (1.0f - z) * hh) : hp;
            hnext[(size_t)b * NH + u] = hn;
            const u16 hi = f2bf(hn);
            const u16 lo = f2bf(hn - bf2f(hi));
            const size_t so = (((size_t)mg * 32 + kcu) * 64 + (brow + lhi)) * 8 + j2;
            hnh[so] = hi;
            hnl[so] = lo;
        }
    }
}

// ---------------- out = h[64,1024] @ Wout[1024,32000] ----------------
__global__ __launch_bounds__(256) void out_mm(const float* __restrict__ h,
                                              const float* __restrict__ Wout,
                                              float* __restrict__ out) {
    const int col = blockIdx.x * 256 + threadIdx.x;  // 32000 = 125*256
    float acc[NB];
#pragma unroll
    for (int b = 0; b < NB; ++b) acc[b] = 0.0f;
    for (int k = 0; k < NH; ++k) {
        const float w = Wout[(size_t)k * NV + col];
#pragma unroll
        for (int b = 0; b < NB; ++b) acc[b] = fmaf(h[b * NH + k], w, acc[b]);
    }
#pragma unroll
    for (int b = 0; b < NB; ++b) out[(size_t)b * NV + col] = acc[b];
}

// ============================================================================
// Fallback (R2 fp32 path) if workspace too small
// ============================================================================
#define NBT 8
#define UT 16
#define KS 16
#define KH (NH / KS)
#define KX (NE / KS)
__device__ __forceinline__ int hrow(int k) { return k + (k >> 6); }
__device__ __forceinline__ int xrow(int k) { return k + (k >> 4); }

__global__ __launch_bounds__(256) void gru_step2(
    const int* __restrict__ tokens, const float* __restrict__ emb,
    const float* __restrict__ Wk, const float* __restrict__ Uk,
    const float* __restrict__ bias,
    const float* __restrict__ h_in, float* __restrict__ h_out, int s)
{
    __shared__ float hs[NH + NH / 64][NBT];
    __shared__ float xs[NE + NE / 16][NBT];
    __shared__ float red[4][NBT][256];
    const int tid = threadIdx.x;
    const int ug = blockIdx.x & 63;
    const int bg = blockIdx.x >> 6;
    for (int i = tid; i < NBT * (NE / 4); i += 256) {
        const int bl = i >> 6; const int e4 = i & 63;
        const int b = bg * NBT + bl;
        const int tok = tokens[b * NS + s];
        const float4 v = ((const float4*)(emb + (size_t)tok * NE))[e4];
        const int k0 = e4 * 4;
        xs[xrow(k0 + 0)][bl] = v.x; xs[xrow(k0 + 1)][bl] = v.y;
        xs[xrow(k0 + 2)][bl] = v.z; xs[xrow(k0 + 3)][bl] = v.w;
    }
    for (int i = tid; i < NBT * (NH / 4); i += 256) {
        const int bl = i >> 8; const int k4 = i & 255;
        const int b = bg * NBT + bl;
        const float4 v = ((const float4*)(h_in + (size_t)b * NH))[k4];
        const int r = hrow(k4 * 4);
        hs[r + 0][bl] = v.x; hs[r + 1][bl] = v.y; hs[r + 2][bl] = v.z; hs[r + 3][bl] = v.w;
    }
    __syncthreads();
    const int ul = tid & 15;
    const int ks = tid >> 4;
    const int u = ug * UT + ul;
    float az[NBT], ar[NBT], axh[NBT], arh[NBT];
#pragma unroll
    for (int b = 0; b < NBT; ++b) { az[b] = 0.f; ar[b] = 0.f; axh[b] = 0.f; arh[b] = 0.f; }
    {
        size_t off = (size_t)(ks * KH) * NH3 + u;
        const int r0 = ks * (KH + 1);
#pragma unroll 4
        for (int kk = 0; kk < KH; ++kk) {
            const float uz = Uk[off], ur = Uk[off + NH], uh = Uk[off + 2 * NH];
            float hv[8];
            *(float4*)&hv[0] = *(const float4*)&hs[r0 + kk][0];
            *(float4*)&hv[4] = *(const float4*)&hs[r0 + kk][4];
#pragma unroll
            for (int b = 0; b < NBT; ++b) {
                az[b] = fmaf(hv[b], uz, az[b]); ar[b] = fmaf(hv[b], ur, ar[b]);
                arh[b] = fmaf(hv[b], uh, arh[b]);
            }
            off += NH3;
        }
    }
    {
        size_t off = (size_t)(ks * KX) * NH3 + u;
        const int r0 = ks * (KX + 1);
#pragma unroll 4
        for (int kk = 0; kk < KX; ++kk) {
            const float wz = Wk[off], wr = Wk[off + NH], wh = Wk[off + 2 * NH];
            float xv[8];
            *(float4*)&xv[0] = *(const float4*)&xs[r0 + kk][0];
            *(float4*)&xv[4] = *(const float4*)&xs[r0 + kk][4];
#pragma unroll
            for (int b = 0; b < NBT; ++b) {
                az[b] = fmaf(xv[b], wz, az[b]); ar[b] = fmaf(xv[b], wr, ar[b]);
                axh[b] = fmaf(xv[b], wh, axh[b]);
            }
            off += NH3;
        }
    }
#pragma unroll
    for (int b = 0; b < NBT; ++b) {
        red[0][b][tid] = az[b]; red[1][b][tid] = ar[b];
        red[2][b][tid] = axh[b]; red[3][b][tid] = arh[b];
    }
    __syncthreads();
    if (tid < 128) {
        const int ul2 = tid & 15;
        const int bl = tid >> 4;
        const int u2 = ug * UT + ul2;
        const int b = bg * NBT + bl;
        float sz = 0.f, sr = 0.f, sxh = 0.f, srh = 0.f;
#pragma unroll
        for (int k2 = 0; k2 < KS; ++k2) {
            const int t2 = k2 * 16 + ul2;
            sz += red[0][bl][t2]; sr += red[1][bl][t2];
            sxh += red[2][bl][t2]; srh += red[3][bl][t2];
        }
        sz += bias[u2] + bias[NH3 + u2];
        sr += bias[NH + u2] + bias[NH3 + NH + u2];
        sxh += bias[2 * NH + u2];
        srh += bias[NH3 + 2 * NH + u2];
        const float z = 1.0f / (1.0f + expf(-sz));
        const float r = 1.0f / (1.0f + expf(-sr));
        const float hh = tanhf(sxh + r * srh);
        const float hp = hs[hrow(u2)][bl];
        const bool m = tokens[b * NS + s] != 0;
        h_out[(size_t)b * NH + u2] = m ? (z * hp + (1.0f - z) * hh) : hp;
    }
}

extern "C" void kernel_launch(void* const* d_in, const int* in_sizes, int n_in,
                              void* d_out, int out_size, void* d_ws, size_t ws_size,
                              hipStream_t stream) {
    const int* tokens = (const int*)d_in[0];
    const float* emb = (const float*)d_in[1];
    const float* Wk = (const float*)d_in[2];
    const float* Uk = (const float*)d_in[3];
    const float* bias = (const float*)d_in[4];
    const float* Wout = (const float*)d_in[5];
    float* out = (float*)d_out;

    const size_t B_ELEMS = (size_t)64 * 120 * 512;   // 3,932,160
    const size_t X_ELEMS = (size_t)NS * 4 * 8 * 512; // 8,388,608
    const size_t H_ELEMS = (size_t)NB * NH;          // 65,536
    const size_t HS_ELEMS = (size_t)4 * 32 * 64 * 8; // 65,536

    size_t off = 0;
    auto take = [&](size_t bytes) { size_t o = off; off += (bytes + 255) & ~255ULL; return o; };
    const size_t oBh = take(B_ELEMS * 2), oBl = take(B_ELEMS * 2);
    const size_t oXh = take(X_ELEMS * 2), oXl = take(X_ELEMS * 2);
    const size_t ohA = take(H_ELEMS * 4), ohB = take(H_ELEMS * 4);
    const size_t osAh = take(HS_ELEMS * 2), osAl = take(HS_ELEMS * 2);
    const size_t osBh = take(HS_ELEMS * 2), osBl = take(HS_ELEMS * 2);

    char* base = (char*)d_ws;

    if (off <= ws_size) {
        u16* Bh = (u16*)(base + oBh); u16* Bl = (u16*)(base + oBl);
        u16* Xh = (u16*)(base + oXh); u16* Xl = (u16*)(base + oXl);
        float* hA = (float*)(base + ohA); float* hB = (float*)(base + ohB);
        u16* sAh = (u16*)(base + osAh); u16* sAl = (u16*)(base + osAl);
        u16* sBh = (u16*)(base + osBh); u16* sBl = (u16*)(base + osBl);

        hipMemsetAsync(hA, 0, H_ELEMS * 4, stream);
        hipMemsetAsync(sAh, 0, HS_ELEMS * 2, stream);
        hipMemsetAsync(sAl, 0, HS_ELEMS * 2, stream);
        pack_uk<<<(int)(B_ELEMS / 256), 256, 0, stream>>>(Wk, Uk, Bh, Bl);
        pack_x<<<(int)(X_ELEMS / 256), 256, 0, stream>>>(tokens, emb, Xh, Xl);

        for (int s = 0; s < NS; ++s) {
            const bool even = (s & 1) == 0;
            const float* hc = even ? hA : hB;
            float* hn = even ? hB : hA;
            const u16* hsh = even ? sAh : sBh;
            const u16* hsl = even ? sAl : sBl;
            u16* hnh = even ? sBh : sAh;
            u16* hnl = even ? sBl : sAl;
            gru_step3<<<256, 512, 0, stream>>>(tokens, Bh, Bl, Xh, Xl, bias,
                                               hc, hsh, hsl, hn, hnh, hnl, s);
        }
        out_mm<<<125, 256, 0, stream>>>(hA, Wout, out);
    } else {
        float* h0 = (float*)d_ws;
        float* h1 = h0 + H_ELEMS;
        hipMemsetAsync(h0, 0, H_ELEMS * 4, stream);
        for (int s = 0; s < NS; ++s) {
            const float* hin = (s & 1) ? h1 : h0;
            float* hout = (s & 1) ? h0 : h1;
            gru_step2<<<512, 256, 0, stream>>>(tokens, emb, Wk, Uk, bias, hin, hout, s);
        }
        out_mm<<<125, 256, 0, stream>>>(h0, Wout, out);
    }
}

// Round 4
// 3978.917 us; speedup vs baseline: 4.2767x; 1.0812x over previous
//
#include <hip/hip_runtime.h>
#include <cstddef>
#include <cstdint>

#define NB 64
#define NS 512
#define NE 256
#define NH 1024
#define NH3 3072
#define NV 32000

typedef unsigned short u16;
typedef unsigned int u32;
typedef __attribute__((ext_vector_type(8))) short short8v;
typedef __attribute__((ext_vector_type(4))) float f32x4;

__device__ __forceinline__ u16 f2bf(float x) {
    u32 u = __float_as_uint(x);
    u32 r = (u + 0x7FFFu + ((u >> 16) & 1u)) >> 16;   // RNE
    return (u16)r;
}
__device__ __forceinline__ float bf2f(u16 h) { return __uint_as_float(((u32)h) << 16); }

#define MFMA16(a, b, c) __builtin_amdgcn_mfma_f32_16x16x32_bf16((a), (b), (c), 0, 0, 0)

// ============================================================================
// Packed B layout: [g:64][slot:120][lane:64][j:8] bf16 (hi and lo arrays).
//   slots 0..39: z kc=slot | 40..79: r kc=slot-40 | 80..87: xh kc=slot-48 | 88..119: rh kc=slot-88
// K-concat: k in [0,1024) = h (Uk), [1024,1280) = x (Wk).
// Fragment (16x16x32): lane l -> col/row = l&15, k = (l>>4)*8 + j.
// ============================================================================
__global__ __launch_bounds__(256) void pack_uk(const float* __restrict__ Wk,
                                               const float* __restrict__ Uk,
                                               u16* __restrict__ Bh, u16* __restrict__ Bl) {
    const int idx = blockIdx.x * 256 + threadIdx.x;   // 64*120*512 total
    const int j = idx & 7;
    const int lane = (idx >> 3) & 63;
    const int slot = (idx >> 9) % 120;
    const int g = idx / (120 * 512);
    int tile, kc;
    if (slot < 40) { tile = 0; kc = slot; }
    else if (slot < 80) { tile = 1; kc = slot - 40; }
    else if (slot < 88) { tile = 2; kc = slot - 48; }
    else { tile = 3; kc = slot - 88; }
    const int k = kc * 32 + ((lane >> 4) << 3) + j;
    const int uu = g * 16 + (lane & 15);
    const int col = (tile == 0) ? uu : (tile == 1) ? (NH + uu) : (2 * NH + uu);
    const float v = (k < NH) ? Uk[(size_t)k * NH3 + col]
                             : Wk[(size_t)(k - NH) * NH3 + col];
    const u16 hi = f2bf(v);
    Bh[idx] = hi;
    Bl[idx] = f2bf(v - bf2f(hi));
}

// X fragments for all steps: [s:512][mg:4][kcx:8][lane:64][j:8] bf16 hi/lo
__global__ __launch_bounds__(256) void pack_x(const int* __restrict__ tokens,
                                              const float* __restrict__ emb,
                                              u16* __restrict__ Xh, u16* __restrict__ Xl) {
    const int idx = blockIdx.x * 256 + threadIdx.x;   // 512*4*8*512 total
    const int j = idx & 7;
    const int lane = (idx >> 3) & 63;
    const int kcx = (idx >> 9) & 7;
    const int mg = (idx >> 12) & 3;
    const int s = idx >> 14;
    const int b = mg * 16 + (lane & 15);
    const int e = kcx * 32 + ((lane >> 4) << 3) + j;
    const int tok = tokens[b * NS + s];
    const float v = emb[(size_t)tok * NE + e];
    const u16 hi = f2bf(v);
    Xh[idx] = hi;
    Xl[idx] = f2bf(v - bf2f(hi));
}

// ============================================================================
// Persistent scan: 256 blocks = mg(4) x g(64), blockIdx = mg*64+g -> XCD = g%8.
// 512 threads = 8 waves; wave w owns kc = w + 8t, t=0..4 (t<4: h-part, t=4: x).
// B fragments live in registers for all 512 steps. Grid barrier between steps.
// bar layout (ints): leaf[l] at bar[l*32] (l=0..7), root at bar[256].
// ============================================================================
__global__ __launch_bounds__(512, 2) void gru_scan(
    const int* __restrict__ tokens,
    const u16* __restrict__ Bh, const u16* __restrict__ Bl,
    const u16* __restrict__ Xh, const u16* __restrict__ Xl,
    const float* __restrict__ bias,
    float* __restrict__ hA, float* __restrict__ hB,
    u16* __restrict__ sAh, u16* __restrict__ sAl,
    u16* __restrict__ sBh, u16* __restrict__ sBl,
    int* __restrict__ bar)
{
    __shared__ f32x4 red[8][4][64];   // 32 KB
    __shared__ f32x4 preS[4][64];     // 4 KB

    const int g = blockIdx.x & 63;
    const int mg = blockIdx.x >> 6;
    const int tid = threadIdx.x;
    const int w = tid >> 6;
    const int lane = tid & 63;
    const size_t laneo = (size_t)lane * 8;
    const size_t bbase = (size_t)g * 120 * 512;

    // ---- preload B fragments into registers (held across all 512 steps) ----
    short8v Bz_h[5], Bz_l[5], Br_h[5], Br_l[5], B3_h[5], B3_l[5];
#pragma unroll
    for (int t = 0; t < 5; ++t) {
        const int kc = w + 8 * t;
        const size_t oz = bbase + (size_t)kc * 512 + laneo;
        const size_t orr = bbase + (size_t)(40 + kc) * 512 + laneo;
        const size_t o3 = bbase + (size_t)((t < 4) ? (88 + kc) : (48 + kc)) * 512 + laneo;
        Bz_h[t] = *(const short8v*)(Bh + oz);
        Bz_l[t] = *(const short8v*)(Bl + oz);
        Br_h[t] = *(const short8v*)(Bh + orr);
        Br_l[t] = *(const short8v*)(Bl + orr);
        B3_h[t] = *(const short8v*)(Bh + o3);
        B3_l[t] = *(const short8v*)(Bl + o3);
    }

    // ---- gate-thread constants (valid for tid < 256) ----
    const int ll = tid & 63;
    const int q = tid >> 6;                       // reduce: tile id; gates: j-component
    const int u = g * 16 + (ll & 15);
    const int brow = ((ll >> 4) << 2) + (q & 3);
    const int b = mg * 16 + brow;
    const float bz = bias[u] + bias[NH3 + u];
    const float br = bias[NH + u] + bias[NH3 + NH + u];
    const float bxh = bias[2 * NH + u];
    const float brh = bias[NH3 + 2 * NH + u];
    const size_t hoff = (size_t)b * NH + u;       // fp32 h element this thread owns
    const size_t soA = (((size_t)mg * 32 + (u >> 5)) * 64 +
                        (brow + (((u & 31) >> 3) << 4))) * 8 + (u & 7);
    const int* tokp = tokens + b * NS;

    const int leaf = blockIdx.x & 7;              // = XCD id
    int* leafp = bar + leaf * 32;
    int* rootp = bar + 256;
    int root_target = 0;

    for (int s = 0; s < NS; ++s) {
        const bool even = !(s & 1);
        const u16* hsh = even ? sAh : sBh;
        const u16* hsl = even ? sAl : sBl;
        u16* hnh = even ? sBh : sAh;
        u16* hnl = even ? sBl : sAl;
        const float* hc = even ? hA : hB;
        float* hn = even ? hB : hA;

        f32x4 accz = {0.f, 0.f, 0.f, 0.f};
        f32x4 accr = accz, accxh = accz, accrh = accz;

#pragma unroll
        for (int t = 0; t < 5; ++t) {
            const int kc = w + 8 * t;
            const u16 *pah, *pal;
            if (t < 4) {
                const size_t aoff = ((size_t)(mg * 32 + kc) * 64) * 8 + laneo;
                pah = hsh + aoff; pal = hsl + aoff;
            } else {
                const size_t aoff = ((((size_t)s * 4 + mg) * 8 + (kc - 32)) * 64) * 8 + laneo;
                pah = Xh + aoff; pal = Xl + aoff;
            }
            const short8v Ah = *(const short8v*)pah;
            const short8v Al = *(const short8v*)pal;
            accz = MFMA16(Ah, Bz_h[t], accz);
            accr = MFMA16(Ah, Br_h[t], accr);
            if (t < 4) {
                accrh = MFMA16(Ah, B3_h[t], accrh);
                accrh = MFMA16(Al, B3_h[t], accrh);
                accrh = MFMA16(Ah, B3_l[t], accrh);
            } else {
                accxh = MFMA16(Ah, B3_h[t], accxh);
                accxh = MFMA16(Al, B3_h[t], accxh);
                accxh = MFMA16(Ah, B3_l[t], accxh);
            }
            accz = MFMA16(Al, Bz_h[t], accz);
            accz = MFMA16(Ah, Bz_l[t], accz);
            accr = MFMA16(Al, Br_h[t], accr);
            accr = MFMA16(Ah, Br_l[t], accr);
        }

        red[w][0][lane] = accz;
        red[w][1][lane] = accr;
        red[w][2][lane] = accxh;
        red[w][3][lane] = accrh;
        __syncthreads();

        if (tid < 256) {
            f32x4 sum = red[0][q][ll];
#pragma unroll
            for (int w2 = 1; w2 < 8; ++w2) {
                const f32x4 v = red[w2][q][ll];
                sum.x += v.x; sum.y += v.y; sum.z += v.z; sum.w += v.w;
            }
            preS[q][ll] = sum;
        }
        __syncthreads();

        if (tid < 256) {
            const float pz = ((const float*)&preS[0][ll])[q];
            const float pr = ((const float*)&preS[1][ll])[q];
            const float pxh = ((const float*)&preS[2][ll])[q];
            const float prh = ((const float*)&preS[3][ll])[q];
            const float z = 1.0f / (1.0f + expf(-(pz + bz)));
            const float r = 1.0f / (1.0f + expf(-(pr + br)));
            const float hh = tanhf(pxh + bxh + r * (prh + brh));
            const float hp = hc[hoff];
            const bool m = tokp[s] != 0;
            const float hnv = m ? (z * hp + (1.0f - z) * hh) : hp;
            hn[hoff] = hnv;
            const u16 hi = f2bf(hnv);
            hnh[soA] = hi;
            hnl[soA] = f2bf(hnv - bf2f(hi));
        }

        // ---- grid barrier (stores of all waves drained by this syncthreads) ----
        __syncthreads();
        root_target += 8;
        if (tid == 0) {
            const int v = __hip_atomic_fetch_add(leafp, 1, __ATOMIC_RELAXED,
                                                 __HIP_MEMORY_SCOPE_AGENT);
            if ((v & 31) == 31) {   // last block of this XCD this step
                __builtin_amdgcn_fence(__ATOMIC_RELEASE, "agent");   // L2 writeback
                __hip_atomic_fetch_add(rootp, 1, __ATOMIC_RELAXED,
                                       __HIP_MEMORY_SCOPE_AGENT);
            }
            while (__hip_atomic_load(rootp, __ATOMIC_RELAXED,
                                     __HIP_MEMORY_SCOPE_AGENT) < root_target) {
                __builtin_amdgcn_s_sleep(2);
            }
            __builtin_amdgcn_fence(__ATOMIC_ACQUIRE, "agent");       // inv L1/L2
        }
        __syncthreads();
    }
}

// ---------------- out = h[64,1024] @ Wout[1024,32000] ----------------
// 500 blocks x 256 thr; block = 64 cols, K split 4 ways; LDS combine.
__global__ __launch_bounds__(256) void out_mm2(const float* __restrict__ h,
                                               const float* __restrict__ Wout,
                                               float* __restrict__ out) {
    __shared__ float red[4][NB][64];   // 64 KB
    const int cl = threadIdx.x & 63;
    const int ks = threadIdx.x >> 6;
    const int col = blockIdx.x * 64 + cl;
    float acc[NB];
#pragma unroll
    for (int b = 0; b < NB; ++b) acc[b] = 0.0f;
    const int k0 = ks * 256;
    for (int k = k0; k < k0 + 256; ++k) {
        const float wv = Wout[(size_t)k * NV + col];
#pragma unroll
        for (int b = 0; b < NB; ++b) acc[b] = fmaf(h[b * NH + k], wv, acc[b]);
    }
#pragma unroll
    for (int b = 0; b < NB; ++b) red[ks][b][cl] = acc[b];
    __syncthreads();
    // 256 threads x 16 outputs: out[b][col0+cl2]
    for (int i = threadIdx.x; i < NB * 64; i += 256) {
        const int b = i >> 6;
        const int c2 = i & 63;
        const float v = red[0][b][c2] + red[1][b][c2] + red[2][b][c2] + red[3][b][c2];
        out[(size_t)b * NV + blockIdx.x * 64 + c2] = v;
    }
}

// ============================================================================
// Fallback (fp32, small-ws) — R2 path
// ============================================================================
#define NBT 8
#define UT 16
#define KS 16
#define KH (NH / KS)
#define KX (NE / KS)
__device__ __forceinline__ int hrow(int k) { return k + (k >> 6); }
__device__ __forceinline__ int xrow(int k) { return k + (k >> 4); }

__global__ __launch_bounds__(256) void gru_step2(
    const int* __restrict__ tokens, const float* __restrict__ emb,
    const float* __restrict__ Wk, const float* __restrict__ Uk,
    const float* __restrict__ bias,
    const float* __restrict__ h_in, float* __restrict__ h_out, int s)
{
    __shared__ float hs[NH + NH / 64][NBT];
    __shared__ float xs[NE + NE / 16][NBT];
    __shared__ float red[4][NBT][256];
    const int tid = threadIdx.x;
    const int ug = blockIdx.x & 63;
    const int bg = blockIdx.x >> 6;
    for (int i = tid; i < NBT * (NE / 4); i += 256) {
        const int bl = i >> 6; const int e4 = i & 63;
        const int b = bg * NBT + bl;
        const int tok = tokens[b * NS + s];
        const float4 v = ((const float4*)(emb + (size_t)tok * NE))[e4];
        const int k0 = e4 * 4;
        xs[xrow(k0 + 0)][bl] = v.x; xs[xrow(k0 + 1)][bl] = v.y;
        xs[xrow(k0 + 2)][bl] = v.z; xs[xrow(k0 + 3)][bl] = v.w;
    }
    for (int i = tid; i < NBT * (NH / 4); i += 256) {
        const int bl = i >> 8; const int k4 = i & 255;
        const int b = bg * NBT + bl;
        const float4 v = ((const float4*)(h_in + (size_t)b * NH))[k4];
        const int r = hrow(k4 * 4);
        hs[r + 0][bl] = v.x; hs[r + 1][bl] = v.y; hs[r + 2][bl] = v.z; hs[r + 3][bl] = v.w;
    }
    __syncthreads();
    const int ul = tid & 15;
    const int ks = tid >> 4;
    const int u = ug * UT + ul;
    float az[NBT], ar[NBT], axh[NBT], arh[NBT];
#pragma unroll
    for (int b = 0; b < NBT; ++b) { az[b] = 0.f; ar[b] = 0.f; axh[b] = 0.f; arh[b] = 0.f; }
    {
        size_t off = (size_t)(ks * KH) * NH3 + u;
        const int r0 = ks * (KH + 1);
#pragma unroll 4
        for (int kk = 0; kk < KH; ++kk) {
            const float uz = Uk[off], ur = Uk[off + NH], uh = Uk[off + 2 * NH];
            float hv[8];
            *(float4*)&hv[0] = *(const float4*)&hs[r0 + kk][0];
            *(float4*)&hv[4] = *(const float4*)&hs[r0 + kk][4];
#pragma unroll
            for (int b = 0; b < NBT; ++b) {
                az[b] = fmaf(hv[b], uz, az[b]); ar[b] = fmaf(hv[b], ur, ar[b]);
                arh[b] = fmaf(hv[b], uh, arh[b]);
            }
            off += NH3;
        }
    }
    {
        size_t off = (size_t)(ks * KX) * NH3 + u;
        const int r0 = ks * (KX + 1);
#pragma unroll 4
        for (int kk = 0; kk < KX; ++kk) {
            const float wz = Wk[off], wr = Wk[off + NH], wh = Wk[off + 2 * NH];
            float xv[8];
            *(float4*)&xv[0] = *(const float4*)&xs[r0 + kk][0];
            *(float4*)&xv[4] = *(const float4*)&xs[r0 + kk][4];
#pragma unroll
            for (int b = 0; b < NBT; ++b) {
                az[b] = fmaf(xv[b], wz, az[b]); ar[b] = fmaf(xv[b], wr, ar[b]);
                axh[b] = fmaf(xv[b], wh, axh[b]);
            }
            off += NH3;
        }
    }
#pragma unroll
    for (int b = 0; b < NBT; ++b) {
        red[0][b][tid] = az[b]; red[1][b][tid] = ar[b];
        red[2][b][tid] = axh[b]; red[3][b][tid] = arh[b];
    }
    __syncthreads();
    if (tid < 128) {
        const int ul2 = tid & 15;
        const int bl = tid >> 4;
        const int u2 = ug * UT + ul2;
        const int b = bg * NBT + bl;
        float sz = 0.f, sr = 0.f, sxh = 0.f, srh = 0.f;
#pragma unroll
        for (int k2 = 0; k2 < KS; ++k2) {
            const int t2 = k2 * 16 + ul2;
            sz += red[0][bl][t2]; sr += red[1][bl][t2];
            sxh += red[2][bl][t2]; srh += red[3][bl][t2];
        }
        sz += bias[u2] + bias[NH3 + u2];
        sr += bias[NH + u2] + bias[NH3 + NH + u2];
        sxh += bias[2 * NH + u2];
        srh += bias[NH3 + 2 * NH + u2];
        const float z = 1.0f / (1.0f + expf(-sz));
        const float r = 1.0f / (1.0f + expf(-sr));
        const float hh = tanhf(sxh + r * srh);
        const float hp = hs[hrow(u2)][bl];
        const bool m = tokens[b * NS + s] != 0;
        h_out[(size_t)b * NH + u2] = m ? (z * hp + (1.0f - z) * hh) : hp;
    }
}

extern "C" void kernel_launch(void* const* d_in, const int* in_sizes, int n_in,
                              void* d_out, int out_size, void* d_ws, size_t ws_size,
                              hipStream_t stream) {
    const int* tokens = (const int*)d_in[0];
    const float* emb = (const float*)d_in[1];
    const float* Wk = (const float*)d_in[2];
    const float* Uk = (const float*)d_in[3];
    const float* bias = (const float*)d_in[4];
    const float* Wout = (const float*)d_in[5];
    float* out = (float*)d_out;

    const size_t B_ELEMS = (size_t)64 * 120 * 512;   // 3,932,160
    const size_t X_ELEMS = (size_t)NS * 4 * 8 * 512; // 8,388,608
    const size_t H_ELEMS = (size_t)NB * NH;          // 65,536
    const size_t HS_ELEMS = (size_t)4 * 32 * 64 * 8; // 65,536

    size_t off = 0;
    auto take = [&](size_t bytes) { size_t o = off; off += (bytes + 255) & ~255ULL; return o; };
    const size_t oBh = take(B_ELEMS * 2), oBl = take(B_ELEMS * 2);
    const size_t oXh = take(X_ELEMS * 2), oXl = take(X_ELEMS * 2);
    const size_t ohA = take(H_ELEMS * 4), ohB = take(H_ELEMS * 4);
    const size_t osAh = take(HS_ELEMS * 2), osAl = take(HS_ELEMS * 2);
    const size_t osBh = take(HS_ELEMS * 2), osBl = take(HS_ELEMS * 2);
    const size_t obar = take(512 * 4);

    char* base = (char*)d_ws;

    if (off <= ws_size) {
        u16* Bh = (u16*)(base + oBh); u16* Bl = (u16*)(base + oBl);
        u16* Xh = (u16*)(base + oXh); u16* Xl = (u16*)(base + oXl);
        float* hA = (float*)(base + ohA); float* hB = (float*)(base + ohB);
        u16* sAh = (u16*)(base + osAh); u16* sAl = (u16*)(base + osAl);
        u16* sBh = (u16*)(base + osBh); u16* sBl = (u16*)(base + osBl);
        int* bar = (int*)(base + obar);

        hipMemsetAsync(hA, 0, H_ELEMS * 4, stream);
        hipMemsetAsync(sAh, 0, HS_ELEMS * 2, stream);
        hipMemsetAsync(sAl, 0, HS_ELEMS * 2, stream);
        hipMemsetAsync(bar, 0, 512 * 4, stream);
        pack_uk<<<(int)(B_ELEMS / 256), 256, 0, stream>>>(Wk, Uk, Bh, Bl);
        pack_x<<<(int)(X_ELEMS / 256), 256, 0, stream>>>(tokens, emb, Xh, Xl);

        gru_scan<<<256, 512, 0, stream>>>(tokens, Bh, Bl, Xh, Xl, bias,
                                          hA, hB, sAh, sAl, sBh, sBl, bar);
        out_mm2<<<500, 256, 0, stream>>>(hA, Wout, out);
    } else {
        float* h0 = (float*)d_ws;
        float* h1 = h0 + H_ELEMS;
        hipMemsetAsync(h0, 0, H_ELEMS * 4, stream);
        for (int s = 0; s < NS; ++s) {
            const float* hin = (s & 1) ? h1 : h0;
            float* hout = (s & 1) ? h0 : h1;
            gru_step2<<<512, 256, 0, stream>>>(tokens, emb, Wk, Uk, bias, hin, hout, s);
        }
        out_mm2<<<500, 256, 0, stream>>>(h0, Wout, out);
    }
}

// Round 5
// 2824.716 us; speedup vs baseline: 6.0242x; 1.4086x over previous
//
#include <hip/hip_runtime.h>
#include <cstddef>
#include <cstdint>

#define NB 64
#define NS 512
#define NE 256
#define NH 1024
#define NH3 3072
#define NV 32000

typedef unsigned short u16;
typedef unsigned int u32;
typedef unsigned long long u64;
typedef __attribute__((ext_vector_type(8))) short short8v;
typedef __attribute__((ext_vector_type(4))) float f32x4;

__device__ __forceinline__ u16 f2bf(float x) {
    u32 u = __float_as_uint(x);
    u32 r = (u + 0x7FFFu + ((u >> 16) & 1u)) >> 16;   // RNE
    return (u16)r;
}
__device__ __forceinline__ float bf2f(u16 h) { return __uint_as_float(((u32)h) << 16); }

#define MFMA16(a, b, c) __builtin_amdgcn_mfma_f32_16x16x32_bf16((a), (b), (c), 0, 0, 0)

// ============================================================================
// Packed B layout: [g:64][slot:120][lane:64][j:8] bf16 (hi and lo arrays).
//   slots 0..39: z kc=slot | 40..79: r kc=slot-40 | 80..87: xh kc=slot-48 | 88..119: rh kc=slot-88
// K-concat: k in [0,1024) = h (Uk), [1024,1280) = x (Wk).
// Fragment (16x16x32): lane l -> col/row = l&15, k = (l>>4)*8 + j.
// ============================================================================
__global__ __launch_bounds__(256) void pack_uk(const float* __restrict__ Wk,
                                               const float* __restrict__ Uk,
                                               u16* __restrict__ Bh, u16* __restrict__ Bl) {
    const int idx = blockIdx.x * 256 + threadIdx.x;   // 64*120*512 total
    const int j = idx & 7;
    const int lane = (idx >> 3) & 63;
    const int slot = (idx >> 9) % 120;
    const int g = idx / (120 * 512);
    int tile, kc;
    if (slot < 40) { tile = 0; kc = slot; }
    else if (slot < 80) { tile = 1; kc = slot - 40; }
    else if (slot < 88) { tile = 2; kc = slot - 48; }
    else { tile = 3; kc = slot - 88; }
    const int k = kc * 32 + ((lane >> 4) << 3) + j;
    const int uu = g * 16 + (lane & 15);
    const int col = (tile == 0) ? uu : (tile == 1) ? (NH + uu) : (2 * NH + uu);
    const float v = (k < NH) ? Uk[(size_t)k * NH3 + col]
                             : Wk[(size_t)(k - NH) * NH3 + col];
    const u16 hi = f2bf(v);
    Bh[idx] = hi;
    Bl[idx] = f2bf(v - bf2f(hi));
}

// X fragments for all steps: [s:512][mg:4][kcx:8][lane:64][j:8] bf16 hi/lo
__global__ __launch_bounds__(256) void pack_x(const int* __restrict__ tokens,
                                              const float* __restrict__ emb,
                                              u16* __restrict__ Xh, u16* __restrict__ Xl) {
    const int idx = blockIdx.x * 256 + threadIdx.x;   // 512*4*8*512 total
    const int j = idx & 7;
    const int lane = (idx >> 3) & 63;
    const int kcx = (idx >> 9) & 7;
    const int mg = (idx >> 12) & 3;
    const int s = idx >> 14;
    const int b = mg * 16 + (lane & 15);
    const int e = kcx * 32 + ((lane >> 4) << 3) + j;
    const int tok = tokens[b * NS + s];
    const float v = emb[(size_t)tok * NE + e];
    const u16 hi = f2bf(v);
    Xh[idx] = hi;
    Xl[idx] = f2bf(v - bf2f(hi));
}

// ============================================================================
// Persistent scan: 256 blocks = mg(4) x g(64), blockIdx = mg*64+g -> XCD = g%8.
// 512 threads = 8 waves; wave w owns kc = w + 8t, t=0..4 (t<4: h-part, t=4: x).
// B fragments pinned in VGPRs across all 512 steps (asm pin defeats remat).
// No fences: cross-step h exchange via device-coherent (sc0 sc1) atomics;
// fp32 h carried in gate-thread registers. Per-mg 2-level barrier.
// bar ints: sub[(mg*8+sg)*32] in [0,1024), root[mg] at [1024 + mg*32].
// ============================================================================
__global__ __launch_bounds__(512, 2) void gru_scan(
    const int* __restrict__ tokens,
    const u16* __restrict__ Bh, const u16* __restrict__ Bl,
    const u16* __restrict__ Xh, const u16* __restrict__ Xl,
    const float* __restrict__ bias,
    float* __restrict__ hA,
    u16* __restrict__ sAh, u16* __restrict__ sAl,
    u16* __restrict__ sBh, u16* __restrict__ sBl,
    int* __restrict__ bar)
{
    __shared__ f32x4 red[8][4][64];   // 32 KB
    __shared__ f32x4 preS[4][64];     // 4 KB

    const int g = blockIdx.x & 63;
    const int mg = blockIdx.x >> 6;
    const int tid = threadIdx.x;
    const int w = tid >> 6;
    const int lane = tid & 63;
    const size_t laneo = (size_t)lane * 8;
    const size_t bbase = (size_t)g * 120 * 512;

    // ---- preload B fragments into registers (held across all 512 steps) ----
    short8v Bz_h[5], Bz_l[5], Br_h[5], Br_l[5], B3_h[5], B3_l[5];
#pragma unroll
    for (int t = 0; t < 5; ++t) {
        const int kc = w + 8 * t;
        const size_t oz = bbase + (size_t)kc * 512 + laneo;
        const size_t orr = bbase + (size_t)(40 + kc) * 512 + laneo;
        const size_t o3 = bbase + (size_t)((t < 4) ? (88 + kc) : (48 + kc)) * 512 + laneo;
        Bz_h[t] = *(const short8v*)(Bh + oz);
        Bz_l[t] = *(const short8v*)(Bl + oz);
        Br_h[t] = *(const short8v*)(Bh + orr);
        Br_l[t] = *(const short8v*)(Bl + orr);
        B3_h[t] = *(const short8v*)(Bh + o3);
        B3_l[t] = *(const short8v*)(Bl + o3);
    }

    // ---- gate-thread constants (valid for tid < 256) ----
    const int ll = tid & 63;
    const int q = tid >> 6;                       // reduce: tile id; gates: j-component
    const int u = g * 16 + (ll & 15);
    const int brow = ((ll >> 4) << 2) + (q & 3);
    const int b = mg * 16 + brow;
    const float bz = bias[u] + bias[NH3 + u];
    const float br = bias[NH + u] + bias[NH3 + NH + u];
    const float bxh = bias[2 * NH + u];
    const float brh = bias[NH3 + 2 * NH + u];
    const size_t hoff = (size_t)b * NH + u;
    const size_t soA = (((size_t)mg * 32 + (u >> 5)) * 64 +
                        (brow + (((u & 31) >> 3) << 4))) * 8 + (u & 7);
    const int* tokp = tokens + b * NS;
    float hp = 0.0f;                              // fp32 h carried in register

    int* subp = bar + ((size_t)(mg * 8 + (g >> 3)) * 32);
    int* rootp = bar + 1024 + mg * 32;

    union AU { u64 q2[2]; short8v v; };

    for (int s = 0; s < NS; ++s) {
        const bool even = !(s & 1);
        const u16* hsh = even ? sAh : sBh;
        const u16* hsl = even ? sAl : sBl;
        u16* hnh = even ? sBh : sAh;
        u16* hnl = even ? sBl : sAl;

        // pin B in registers: asm redefines values -> cannot be rematerialized
        asm volatile("" : "+v"(Bz_h[0]), "+v"(Bz_h[1]), "+v"(Bz_h[2]), "+v"(Bz_h[3]), "+v"(Bz_h[4]));
        asm volatile("" : "+v"(Bz_l[0]), "+v"(Bz_l[1]), "+v"(Bz_l[2]), "+v"(Bz_l[3]), "+v"(Bz_l[4]));
        asm volatile("" : "+v"(Br_h[0]), "+v"(Br_h[1]), "+v"(Br_h[2]), "+v"(Br_h[3]), "+v"(Br_h[4]));
        asm volatile("" : "+v"(Br_l[0]), "+v"(Br_l[1]), "+v"(Br_l[2]), "+v"(Br_l[3]), "+v"(Br_l[4]));
        asm volatile("" : "+v"(B3_h[0]), "+v"(B3_h[1]), "+v"(B3_h[2]), "+v"(B3_h[3]), "+v"(B3_h[4]));
        asm volatile("" : "+v"(B3_l[0]), "+v"(B3_l[1]), "+v"(B3_l[2]), "+v"(B3_l[3]), "+v"(B3_l[4]));

        f32x4 accz = {0.f, 0.f, 0.f, 0.f};
        f32x4 accr = accz, accxh = accz, accrh = accz;

#pragma unroll
        for (int t = 0; t < 5; ++t) {
            const int kc = w + 8 * t;
            short8v Ah, Al;
            if (t < 4) {
                // device-coherent (L3) loads of h fragments from other XCDs
                const size_t aoff = ((size_t)(mg * 32 + kc) * 64) * 8 + laneo;
                AU ah, al;
                const u64* ph = (const u64*)(hsh + aoff);
                const u64* pl = (const u64*)(hsl + aoff);
                ah.q2[0] = __hip_atomic_load(ph + 0, __ATOMIC_RELAXED, __HIP_MEMORY_SCOPE_AGENT);
                ah.q2[1] = __hip_atomic_load(ph + 1, __ATOMIC_RELAXED, __HIP_MEMORY_SCOPE_AGENT);
                al.q2[0] = __hip_atomic_load(pl + 0, __ATOMIC_RELAXED, __HIP_MEMORY_SCOPE_AGENT);
                al.q2[1] = __hip_atomic_load(pl + 1, __ATOMIC_RELAXED, __HIP_MEMORY_SCOPE_AGENT);
                Ah = ah.v; Al = al.v;
            } else {
                // X fragments: written before kernel launch, normal cached loads
                const size_t aoff = ((((size_t)s * 4 + mg) * 8 + (kc - 32)) * 64) * 8 + laneo;
                Ah = *(const short8v*)(Xh + aoff);
                Al = *(const short8v*)(Xl + aoff);
            }
            accz = MFMA16(Ah, Bz_h[t], accz);
            accr = MFMA16(Ah, Br_h[t], accr);
            if (t < 4) {
                accrh = MFMA16(Ah, B3_h[t], accrh);
                accrh = MFMA16(Al, B3_h[t], accrh);
                accrh = MFMA16(Ah, B3_l[t], accrh);
            } else {
                accxh = MFMA16(Ah, B3_h[t], accxh);
                accxh = MFMA16(Al, B3_h[t], accxh);
                accxh = MFMA16(Ah, B3_l[t], accxh);
            }
            accz = MFMA16(Al, Bz_h[t], accz);
            accz = MFMA16(Ah, Bz_l[t], accz);
            accr = MFMA16(Al, Br_h[t], accr);
            accr = MFMA16(Ah, Br_l[t], accr);
        }

        red[w][0][lane] = accz;
        red[w][1][lane] = accr;
        red[w][2][lane] = accxh;
        red[w][3][lane] = accrh;
        __syncthreads();

        if (tid < 256) {
            f32x4 sum = red[0][q][ll];
#pragma unroll
            for (int w2 = 1; w2 < 8; ++w2) {
                const f32x4 v = red[w2][q][ll];
                sum.x += v.x; sum.y += v.y; sum.z += v.z; sum.w += v.w;
            }
            preS[q][ll] = sum;
        }
        __syncthreads();

        if (tid < 256) {
            const float pz = ((const float*)&preS[0][ll])[q];
            const float pr = ((const float*)&preS[1][ll])[q];
            const float pxh = ((const float*)&preS[2][ll])[q];
            const float prh = ((const float*)&preS[3][ll])[q];
            const float z = 1.0f / (1.0f + expf(-(pz + bz)));
            const float r = 1.0f / (1.0f + expf(-(pr + br)));
            const float hh = tanhf(pxh + bxh + r * (prh + brh));
            const bool m = tokp[s] != 0;
            const float hnv = m ? (z * hp + (1.0f - z) * hh) : hp;
            hp = hnv;
            if (s < NS - 1) {
                const u16 hi = f2bf(hnv);
                const u16 lo = f2bf(hnv - bf2f(hi));
                // device-coherent write-through so other XCDs see it in L3
                __hip_atomic_store(hnh + soA, hi, __ATOMIC_RELAXED, __HIP_MEMORY_SCOPE_AGENT);
                __hip_atomic_store(hnl + soA, lo, __ATOMIC_RELAXED, __HIP_MEMORY_SCOPE_AGENT);
            }
        }

        if (s < NS - 1) {
            __syncthreads();   // drains all waves' vmem (stores at coherence point)
            if (tid == 0) {
                const int v = __hip_atomic_fetch_add(subp, 1, __ATOMIC_RELAXED,
                                                     __HIP_MEMORY_SCOPE_AGENT);
                if ((v & 7) == 7) {   // last of this 8-block subgroup this step
                    __hip_atomic_fetch_add(rootp, 1, __ATOMIC_RELAXED,
                                           __HIP_MEMORY_SCOPE_AGENT);
                }
                const int tgt = 8 * (s + 1);
                while (__hip_atomic_load(rootp, __ATOMIC_RELAXED,
                                         __HIP_MEMORY_SCOPE_AGENT) < tgt) {
                    __builtin_amdgcn_s_sleep(1);
                }
            }
            __syncthreads();
        }
    }

    if (tid < 256) hA[hoff] = hp;   // final h for out_mm (normal store)
}

// ---------------- out = h[64,1024] @ Wout[1024,32000] ----------------
__global__ __launch_bounds__(256) void out_mm2(const float* __restrict__ h,
                                               const float* __restrict__ Wout,
                                               float* __restrict__ out) {
    __shared__ float red[4][NB][64];   // 64 KB
    const int cl = threadIdx.x & 63;
    const int ks = threadIdx.x >> 6;
    const int col = blockIdx.x * 64 + cl;
    float acc[NB];
#pragma unroll
    for (int b = 0; b < NB; ++b) acc[b] = 0.0f;
    const int k0 = ks * 256;
    for (int k = k0; k < k0 + 256; ++k) {
        const float wv = Wout[(size_t)k * NV + col];
#pragma unroll
        for (int b = 0; b < NB; ++b) acc[b] = fmaf(h[b * NH + k], wv, acc[b]);
    }
#pragma unroll
    for (int b = 0; b < NB; ++b) red[ks][b][cl] = acc[b];
    __syncthreads();
    for (int i = threadIdx.x; i < NB * 64; i += 256) {
        const int b = i >> 6;
        const int c2 = i & 63;
        const float v = red[0][b][c2] + red[1][b][c2] + red[2][b][c2] + red[3][b][c2];
        out[(size_t)b * NV + blockIdx.x * 64 + c2] = v;
    }
}

// ============================================================================
// Fallback (fp32, small-ws) — R2 path
// ============================================================================
#define NBT 8
#define UT 16
#define KS 16
#define KH (NH / KS)
#define KX (NE / KS)
__device__ __forceinline__ int hrow(int k) { return k + (k >> 6); }
__device__ __forceinline__ int xrow(int k) { return k + (k >> 4); }

__global__ __launch_bounds__(256) void gru_step2(
    const int* __restrict__ tokens, const float* __restrict__ emb,
    const float* __restrict__ Wk, const float* __restrict__ Uk,
    const float* __restrict__ bias,
    const float* __restrict__ h_in, float* __restrict__ h_out, int s)
{
    __shared__ float hs[NH + NH / 64][NBT];
    __shared__ float xs[NE + NE / 16][NBT];
    __shared__ float red[4][NBT][256];
    const int tid = threadIdx.x;
    const int ug = blockIdx.x & 63;
    const int bg = blockIdx.x >> 6;
    for (int i = tid; i < NBT * (NE / 4); i += 256) {
        const int bl = i >> 6; const int e4 = i & 63;
        const int b = bg * NBT + bl;
        const int tok = tokens[b * NS + s];
        const float4 v = ((const float4*)(emb + (size_t)tok * NE))[e4];
        const int k0 = e4 * 4;
        xs[xrow(k0 + 0)][bl] = v.x; xs[xrow(k0 + 1)][bl] = v.y;
        xs[xrow(k0 + 2)][bl] = v.z; xs[xrow(k0 + 3)][bl] = v.w;
    }
    for (int i = tid; i < NBT * (NH / 4); i += 256) {
        const int bl = i >> 8; const int k4 = i & 255;
        const int b = bg * NBT + bl;
        const float4 v = ((const float4*)(h_in + (size_t)b * NH))[k4];
        const int r = hrow(k4 * 4);
        hs[r + 0][bl] = v.x; hs[r + 1][bl] = v.y; hs[r + 2][bl] = v.z; hs[r + 3][bl] = v.w;
    }
    __syncthreads();
    const int ul = tid & 15;
    const int ks = tid >> 4;
    const int u = ug * UT + ul;
    float az[NBT], ar[NBT], axh[NBT], arh[NBT];
#pragma unroll
    for (int b = 0; b < NBT; ++b) { az[b] = 0.f; ar[b] = 0.f; axh[b] = 0.f; arh[b] = 0.f; }
    {
        size_t off = (size_t)(ks * KH) * NH3 + u;
        const int r0 = ks * (KH + 1);
#pragma unroll 4
        for (int kk = 0; kk < KH; ++kk) {
            const float uz = Uk[off], ur = Uk[off + NH], uh = Uk[off + 2 * NH];
            float hv[8];
            *(float4*)&hv[0] = *(const float4*)&hs[r0 + kk][0];
            *(float4*)&hv[4] = *(const float4*)&hs[r0 + kk][4];
#pragma unroll
            for (int b = 0; b < NBT; ++b) {
                az[b] = fmaf(hv[b], uz, az[b]); ar[b] = fmaf(hv[b], ur, ar[b]);
                arh[b] = fmaf(hv[b], uh, arh[b]);
            }
            off += NH3;
        }
    }
    {
        size_t off = (size_t)(ks * KX) * NH3 + u;
        const int r0 = ks * (KX + 1);
#pragma unroll 4
        for (int kk = 0; kk < KX; ++kk) {
            const float wz = Wk[off], wr = Wk[off + NH], wh = Wk[off + 2 * NH];
            float xv[8];
            *(float4*)&xv[0] = *(const float4*)&xs[r0 + kk][0];
            *(float4*)&xv[4] = *(const float4*)&xs[r0 + kk][4];
#pragma unroll
            for (int b = 0; b < NBT; ++b) {
                az[b] = fmaf(xv[b], wz, az[b]); ar[b] = fmaf(xv[b], wr, ar[b]);
                axh[b] = fmaf(xv[b], wh, axh[b]);
            }
            off += NH3;
        }
    }
#pragma unroll
    for (int b = 0; b < NBT; ++b) {
        red[0][b][tid] = az[b]; red[1][b][tid] = ar[b];
        red[2][b][tid] = axh[b]; red[3][b][tid] = arh[b];
    }
    __syncthreads();
    if (tid < 128) {
        const int ul2 = tid & 15;
        const int bl = tid >> 4;
        const int u2 = ug * UT + ul2;
        const int b = bg * NBT + bl;
        float sz = 0.f, sr = 0.f, sxh = 0.f, srh = 0.f;
#pragma unroll
        for (int k2 = 0; k2 < KS; ++k2) {
            const int t2 = k2 * 16 + ul2;
            sz += red[0][bl][t2]; sr += red[1][bl][t2];
            sxh += red[2][bl][t2]; srh += red[3][bl][t2];
        }
        sz += bias[u2] + bias[NH3 + u2];
        sr += bias[NH + u2] + bias[NH3 + NH + u2];
        sxh += bias[2 * NH + u2];
        srh += bias[NH3 + 2 * NH + u2];
        const float z = 1.0f / (1.0f + expf(-sz));
        const float r = 1.0f / (1.0f + expf(-sr));
        const float hh = tanhf(sxh + r * srh);
        const float hp = hs[hrow(u2)][bl];
        const bool m = tokens[b * NS + s] != 0;
        h_out[(size_t)b * NH + u2] = m ? (z * hp + (1.0f - z) * hh) : hp;
    }
}

extern "C" void kernel_launch(void* const* d_in, const int* in_sizes, int n_in,
                              void* d_out, int out_size, void* d_ws, size_t ws_size,
                              hipStream_t stream) {
    const int* tokens = (const int*)d_in[0];
    const float* emb = (const float*)d_in[1];
    const float* Wk = (const float*)d_in[2];
    const float* Uk = (const float*)d_in[3];
    const float* bias = (const float*)d_in[4];
    const float* Wout = (const float*)d_in[5];
    float* out = (float*)d_out;

    const size_t B_ELEMS = (size_t)64 * 120 * 512;   // 3,932,160
    const size_t X_ELEMS = (size_t)NS * 4 * 8 * 512; // 8,388,608
    const size_t H_ELEMS = (size_t)NB * NH;          // 65,536
    const size_t HS_ELEMS = (size_t)4 * 32 * 64 * 8; // 65,536

    size_t off = 0;
    auto take = [&](size_t bytes) { size_t o = off; off += (bytes + 255) & ~255ULL; return o; };
    const size_t oBh = take(B_ELEMS * 2), oBl = take(B_ELEMS * 2);
    const size_t oXh = take(X_ELEMS * 2), oXl = take(X_ELEMS * 2);
    const size_t ohA = take(H_ELEMS * 4);
    const size_t osAh = take(HS_ELEMS * 2), osAl = take(HS_ELEMS * 2);
    const size_t osBh = take(HS_ELEMS * 2), osBl = take(HS_ELEMS * 2);
    const size_t obar = take(1152 * 4);

    char* base = (char*)d_ws;

    if (off <= ws_size) {
        u16* Bh = (u16*)(base + oBh); u16* Bl = (u16*)(base + oBl);
        u16* Xh = (u16*)(base + oXh); u16* Xl = (u16*)(base + oXl);
        float* hA = (float*)(base + ohA);
        u16* sAh = (u16*)(base + osAh); u16* sAl = (u16*)(base + osAl);
        u16* sBh = (u16*)(base + osBh); u16* sBl = (u16*)(base + osBl);
        int* bar = (int*)(base + obar);

        hipMemsetAsync(sAh, 0, HS_ELEMS * 2, stream);
        hipMemsetAsync(sAl, 0, HS_ELEMS * 2, stream);
        hipMemsetAsync(bar, 0, 1152 * 4, stream);
        pack_uk<<<(int)(B_ELEMS / 256), 256, 0, stream>>>(Wk, Uk, Bh, Bl);
        pack_x<<<(int)(X_ELEMS / 256), 256, 0, stream>>>(tokens, emb, Xh, Xl);

        gru_scan<<<256, 512, 0, stream>>>(tokens, Bh, Bl, Xh, Xl, bias,
                                          hA, sAh, sAl, sBh, sBl, bar);
        out_mm2<<<500, 256, 0, stream>>>(hA, Wout, out);
    } else {
        float* h0 = (float*)d_ws;
        float* h1 = h0 + H_ELEMS;
        hipMemsetAsync(h0, 0, H_ELEMS * 4, stream);
        for (int s = 0; s < NS; ++s) {
            const float* hin = (s & 1) ? h1 : h0;
            float* hout = (s & 1) ? h0 : h1;
            gru_step2<<<512, 256, 0, stream>>>(tokens, emb, Wk, Uk, bias, hin, hout, s);
        }
        out_mm2<<<500, 256, 0, stream>>>(h0, Wout, out);
    }
}